// Round 9
// baseline (69.382 us; speedup 1.0000x reference)
//
#include <hip/hip_runtime.h>
#include <hip/hip_bf16.h>
#include <cmath>

#define PHI_F   1.6180339887498949f
#define INV2PI  0.15915494309189535f
#define SQRT2F  1.41421356237309505f
#define TLASTF  (63.0f * 1.6180339887498949f)
#define LOG2EF  1.4426950408889634f

typedef __attribute__((ext_vector_type(8))) short bf16x8;
typedef __attribute__((ext_vector_type(4))) float f32x4;

__device__ __forceinline__ unsigned short bf16rn(float x) {
    const unsigned u = __float_as_uint(x);
    return (unsigned short)((u + 0x7fffu + ((u >> 16) & 1u)) >> 16);
}

// 8x fp32 -> bf16x8 (RN-even), inline weight conversion
__device__ __forceinline__ bf16x8 cvt8(float4 a, float4 b) {
    union { bf16x8 v; __hip_bfloat162 h2[4]; } u;
    u.h2[0] = __float22bfloat162_rn(make_float2(a.x, a.y));
    u.h2[1] = __float22bfloat162_rn(make_float2(a.z, a.w));
    u.h2[2] = __float22bfloat162_rn(make_float2(b.x, b.y));
    u.h2[3] = __float22bfloat162_rn(make_float2(b.z, b.w));
    return u.v;
}

__device__ __forceinline__ float silu_add(float h0, float s) {
    const float sig = __builtin_amdgcn_rcpf(
        1.0f + __builtin_amdgcn_exp2f(-LOG2EF * s));
    return h0 + s * sig;
}

// ---------------------------------------------------------------------------
// Node 1: rotation recurrence. 128 blocks x 512 thr (b = bid, d = tid).
// Depth-8 register prefetch hides te-gather latency under the serial sin chain.
// ---------------------------------------------------------------------------
__global__ __launch_bounds__(512) void rinrec_k(
    const int* __restrict__ ids, const float* __restrict__ te,
    float* __restrict__ h, unsigned short* __restrict__ hh)
{
    const int bid = blockIdx.x, tid = threadIdx.x;
    __shared__ int sid[64];
    if (tid < 64) sid[tid] = ids[bid * 64 + tid];
    __syncthreads();
    const int d = tid;
    float wv[2][8], bev[2][8];
    #pragma unroll
    for (int j = 0; j < 8; ++j) {
        const int id = sid[j];
        wv[0][j]  = te[id * 1024 + d];
        bev[0][j] = te[id * 1024 + 512 + d];
    }
    float v = 0.f;
    #pragma unroll
    for (int g = 0; g < 8; ++g) {
        const int cur = g & 1, nxt = cur ^ 1;
        if (g < 7) {
            #pragma unroll
            for (int j = 0; j < 8; ++j) {
                const int id = sid[(g + 1) * 8 + j];
                wv[nxt][j]  = te[id * 1024 + d];
                bev[nxt][j] = te[id * 1024 + 512 + d];
            }
        }
        #pragma unroll
        for (int j = 0; j < 8; ++j) {
            const int t = g * 8 + j;
            const float rlam = __builtin_amdgcn_rcpf(1.0f + fabsf(wv[cur][j]));
            const float a2 = (SQRT2F * INV2PI) * rlam;
            const float b2 = fmaf(2.0f * INV2PI, bev[cur][j],
                                  fmaf((float)t, 2.0f * PHI_F * INV2PI, 0.125f));
            v = __builtin_amdgcn_sinf(__builtin_amdgcn_fractf(fmaf(v, a2, b2)));
        }
    }
    const float u = SQRT2F * v;
    h[bid * 512 + d] = u;
    hh[bid * 512 + d] = bf16rn(u);
}

// ---------------------------------------------------------------------------
// Fused layer node: theta + sincos + pv-partial, one kernel, block-local.
// Grid 128 = (mt 0..7) x (ks 0..7) x (dh 0..1); 512 thr = 8 waves.
//   stage: hA[16][512] bf16 <- FIRST ? hh : h_prev + silu(sum of 8 S-partials)
//          (!FIRST blocks with ks==0&&dh==0 also write h_l fp32 to hout)
//   theta: wave w -> n-frag (ks*128 + w*16), K=512 from LDS; +bias+t; sincos
//          -> ctst[16][256] bf16 in LDS (cols 0..127 ct, 128..255 st)
//   pv:    wave w -> d-range dh*256 + w*32 (2 frags), K=256 (ct|st slice),
//          B = Pr/Pi fp32 cvt'd inline -> partial Sout[ks][m][d] fp32
// Cross-N reduction of the 8 ks-partials happens in the NEXT node's staging.
// ---------------------------------------------------------------------------
template<bool FIRST>
__global__ __launch_bounds__(512) void layer_k(
    const unsigned short* __restrict__ hhin,
    const float* __restrict__ hprev, const float* __restrict__ Sin,
    float* __restrict__ hout,
    const float* __restrict__ Wl, const float* __restrict__ biasl,
    const float* __restrict__ Prl, const float* __restrict__ Pil,
    float* __restrict__ Sout)
{
    __shared__ unsigned short hA[16][520];    // row 1040 B (260 dw = 4 mod 32)
    __shared__ unsigned short ctst[16][264];  // row 528 B  (132 dw = 4 mod 32)
    const int tid = threadIdx.x;
    const int lane = tid & 63, w = tid >> 6;
    const int mt = blockIdx.x >> 4;
    const int ks = (blockIdx.x >> 1) & 7;
    const int dh = blockIdx.x & 1;

    // ---- stage A-tile (16 x 512 bf16) ----
    {
        const int row = tid >> 5;            // 0..15
        const int dc = (tid & 31) * 16;      // 0..496
        const int gm = mt * 16 + row;
        if (FIRST) {
            const uint4 v0 = *(const uint4*)(hhin + (size_t)gm * 512 + dc);
            const uint4 v1 = *(const uint4*)(hhin + (size_t)gm * 512 + dc + 8);
            *(uint4*)&hA[row][dc] = v0;
            *(uint4*)&hA[row][dc + 8] = v1;
        } else {
            const bool wr = (blockIdx.x & 15) == 0;
            #pragma unroll
            for (int j = 0; j < 4; ++j) {
                const int gd = dc + j * 4;
                float4 s = {0.f, 0.f, 0.f, 0.f};
                #pragma unroll
                for (int p = 0; p < 8; ++p) {
                    const float4 q = *(const float4*)(
                        Sin + ((size_t)(p * 128 + gm)) * 512 + gd);
                    s.x += q.x; s.y += q.y; s.z += q.z; s.w += q.w;
                }
                const float4 h0 = *(const float4*)(hprev + (size_t)gm * 512 + gd);
                float4 val;
                val.x = silu_add(h0.x, s.x);
                val.y = silu_add(h0.y, s.y);
                val.z = silu_add(h0.z, s.z);
                val.w = silu_add(h0.w, s.w);
                if (wr) *(float4*)(hout + (size_t)gm * 512 + gd) = val;
                ushort4 u;
                u.x = bf16rn(val.x); u.y = bf16rn(val.y);
                u.z = bf16rn(val.z); u.w = bf16rn(val.w);
                *(ushort4*)&hA[row][gd] = u;
            }
        }
    }
    __syncthreads();

    // ---- theta: wave w -> one 16x16 n-frag, K=512 ----
    {
        const int rr = lane & 15, ko = (lane >> 4) * 8;
        const unsigned short* ap = &hA[rr][ko];
        const float* bp = Wl + (size_t)(ks * 128 + w * 16 + rr) * 512 + ko;
        f32x4 acc = {0.f, 0.f, 0.f, 0.f};
        #pragma unroll
        for (int kk = 0; kk < 512; kk += 32) {
            const bf16x8 ah = *(const bf16x8*)(ap + kk);
            const float4 b0 = *(const float4*)(bp + kk);
            const float4 b1 = *(const float4*)(bp + kk + 4);
            acc = __builtin_amdgcn_mfma_f32_16x16x32_bf16(ah, cvt8(b0, b1), acc, 0, 0, 0);
        }
        const int col = lane & 15, rb = (lane >> 4) * 4;
        const float bn = biasl[ks * 128 + w * 16 + col] + TLASTF;
        #pragma unroll
        for (int r = 0; r < 4; ++r) {
            const float fr = __builtin_amdgcn_fractf((acc[r] + bn) * INV2PI);
            ctst[rb + r][w * 16 + col]       = bf16rn(__builtin_amdgcn_cosf(fr));
            ctst[rb + r][128 + w * 16 + col] = bf16rn(__builtin_amdgcn_sinf(fr));
        }
    }
    __syncthreads();

    // ---- pv: wave w -> d-range dh*256 + w*32 (2 frags), K=256 ----
    {
        const int rr = lane & 15, ko = (lane >> 4) * 8;
        const unsigned short* ap = &ctst[rr][ko];
        const int col = lane & 15, rb = (lane >> 4) * 4;
        #pragma unroll
        for (int f = 0; f < 2; ++f) {
            const int dd = dh * 256 + w * 32 + f * 16;
            const float* bpr = Prl + (size_t)(dd + rr) * 1024 + ks * 128 + ko;
            const float* bpi = Pil + (size_t)(dd + rr) * 1024 + ks * 128 + ko;
            f32x4 acc = {0.f, 0.f, 0.f, 0.f};
            #pragma unroll
            for (int kk = 0; kk < 128; kk += 32) {      // ct part
                const bf16x8 ah = *(const bf16x8*)(ap + kk);
                const float4 b0 = *(const float4*)(bpr + kk);
                const float4 b1 = *(const float4*)(bpr + kk + 4);
                acc = __builtin_amdgcn_mfma_f32_16x16x32_bf16(ah, cvt8(b0, b1), acc, 0, 0, 0);
            }
            #pragma unroll
            for (int kk = 0; kk < 128; kk += 32) {      // st part
                const bf16x8 ah = *(const bf16x8*)(ap + 128 + kk);
                const float4 b0 = *(const float4*)(bpi + kk);
                const float4 b1 = *(const float4*)(bpi + kk + 4);
                acc = __builtin_amdgcn_mfma_f32_16x16x32_bf16(ah, cvt8(b0, b1), acc, 0, 0, 0);
            }
            #pragma unroll
            for (int r = 0; r < 4; ++r)
                Sout[((size_t)(ks * 128 + mt * 16 + rb + r)) * 512 + dd + col] = acc[r];
        }
    }
}

// ---------------------------------------------------------------------------
// Node 4: logits = h2 @ op^T, h2 = h1 + silu(sum of 8 S1-partials) staged
// inline. Grid 64 = (mt 0..7) x (vs 0..7); wave w -> vocab frag vs*128+w*16.
// ---------------------------------------------------------------------------
__global__ __launch_bounds__(512) void logits_k(
    const float* __restrict__ h1, const float* __restrict__ Sin,
    const float* __restrict__ op, float* __restrict__ out)
{
    __shared__ unsigned short hA[16][520];
    const int tid = threadIdx.x;
    const int lane = tid & 63, w = tid >> 6;
    const int mt = blockIdx.x >> 3, vs = blockIdx.x & 7;

    {
        const int row = tid >> 5;
        const int dc = (tid & 31) * 16;
        const int gm = mt * 16 + row;
        #pragma unroll
        for (int j = 0; j < 4; ++j) {
            const int gd = dc + j * 4;
            float4 s = {0.f, 0.f, 0.f, 0.f};
            #pragma unroll
            for (int p = 0; p < 8; ++p) {
                const float4 q = *(const float4*)(
                    Sin + ((size_t)(p * 128 + gm)) * 512 + gd);
                s.x += q.x; s.y += q.y; s.z += q.z; s.w += q.w;
            }
            const float4 h0 = *(const float4*)(h1 + (size_t)gm * 512 + gd);
            ushort4 u;
            u.x = bf16rn(silu_add(h0.x, s.x));
            u.y = bf16rn(silu_add(h0.y, s.y));
            u.z = bf16rn(silu_add(h0.z, s.z));
            u.w = bf16rn(silu_add(h0.w, s.w));
            *(ushort4*)&hA[row][gd] = u;
        }
    }
    __syncthreads();

    {
        const int rr = lane & 15, ko = (lane >> 4) * 8;
        const unsigned short* ap = &hA[rr][ko];
        const float* bp = op + (size_t)(vs * 128 + w * 16 + rr) * 512 + ko;
        f32x4 acc = {0.f, 0.f, 0.f, 0.f};
        #pragma unroll
        for (int kk = 0; kk < 512; kk += 32) {
            const bf16x8 ah = *(const bf16x8*)(ap + kk);
            const float4 b0 = *(const float4*)(bp + kk);
            const float4 b1 = *(const float4*)(bp + kk + 4);
            acc = __builtin_amdgcn_mfma_f32_16x16x32_bf16(ah, cvt8(b0, b1), acc, 0, 0, 0);
        }
        const int col = lane & 15, rb = (lane >> 4) * 4;
        const int n = vs * 128 + w * 16 + col;
        #pragma unroll
        for (int r = 0; r < 4; ++r)
            out[(size_t)(mt * 16 + rb + r) * 1024 + n] = acc[r];
    }
}

// ---------------------------------------------------------------------------
// B=128, S=64, V=1024, D=512, N=1024, L=2 — 4 nodes total.
// ws (floats): h0 65536 | hh 32768(us 65536) | S0 524288 | S1 524288 | h1 65536
// ---------------------------------------------------------------------------
extern "C" void kernel_launch(void* const* d_in, const int* in_sizes, int n_in,
                              void* d_out, int out_size, void* d_ws, size_t ws_size,
                              hipStream_t stream) {
    const int*   ids   = (const int*)d_in[0];
    const float* te    = (const float*)d_in[1];
    const float* W     = (const float*)d_in[2];
    const float* bias  = (const float*)d_in[3];
    const float* Pr    = (const float*)d_in[4];
    const float* Pi    = (const float*)d_in[5];
    const float* oproj = (const float*)d_in[6];
    float* out = (float*)d_out;

    float*          h0 = (float*)d_ws;                    // 65,536 f32
    unsigned short* hh = (unsigned short*)(h0 + 65536);   // 65,536 us
    float*          S0 = (float*)(hh + 65536);            // 524,288 f32
    float*          S1 = S0 + 524288;                     // 524,288 f32
    float*          h1 = S1 + 524288;                     // 65,536 f32

    rinrec_k<<<128, 512, 0, stream>>>(ids, te, h0, hh);

    layer_k<true><<<128, 512, 0, stream>>>(
        hh, nullptr, nullptr, nullptr,
        W, bias, Pr, Pi, S0);

    layer_k<false><<<128, 512, 0, stream>>>(
        nullptr, h0, S0, h1,
        W + 524288, bias + 1024, Pr + 524288, Pi + 524288, S1);

    logits_k<<<64, 512, 0, stream>>>(h1, S1, oproj, out);
}